// Round 1
// baseline (13558.571 us; speedup 1.0000x reference)
//
#include <hip/hip_runtime.h>

#define U_N 100000
#define I_N 50000
#define D_N 64
#define B_N 4
#define E_N 2000000

// ---------------------------------------------------------------------------
// Phase 1: edge scatter. 16 threads per edge, float4 per thread.
// stack_u[b, rows[e], :] += vals[e] * item_emb[cols[e], :]
// stack_i[b, cols[e], :] += vals[e] * user_emb[rows[e], :]
// ---------------------------------------------------------------------------
__global__ void scatter_kernel(const float* __restrict__ user_emb,
                               const float* __restrict__ item_emb,
                               const int* __restrict__ rows,
                               const int* __restrict__ cols,
                               const float* __restrict__ vals,
                               float* __restrict__ stack_u,   // [B,U,D]
                               float* __restrict__ stack_i) { // [B,I,D]
    long long tid = (long long)blockIdx.x * blockDim.x + threadIdx.x;
    long long e  = tid >> 4;            // edge index in [0, B*E)
    int lane = (int)(tid & 15);         // 16 threads x float4 = 64 floats
    if (e >= (long long)B_N * E_N) return;
    int b = (int)(e / E_N);
    int r = rows[e];
    int c = cols[e];
    float v = vals[e];

    const float4* irow = (const float4*)(item_emb + (long long)c * D_N);
    const float4* urow = (const float4*)(user_emb + (long long)r * D_N);
    float4 iv = irow[lane];
    float4 uv = urow[lane];

    float* du = stack_u + ((long long)b * U_N + r) * D_N + lane * 4;
    float* di = stack_i + ((long long)b * I_N + c) * D_N + lane * 4;
    atomicAdd(du + 0, v * iv.x);
    atomicAdd(du + 1, v * iv.y);
    atomicAdd(du + 2, v * iv.z);
    atomicAdd(du + 3, v * iv.w);
    atomicAdd(di + 0, v * uv.x);
    atomicAdd(di + 1, v * uv.y);
    atomicAdd(di + 2, v * uv.z);
    atomicAdd(di + 3, v * uv.w);
}

// ---------------------------------------------------------------------------
// Phase 2: per-row dense transform + sigmoid, in place.
// One 64-thread block per row; lane j computes output column j for all B
// behaviors plus the mean (mean @ W == mean of per-behavior (stack @ W)).
// ---------------------------------------------------------------------------
template <int NROWS>
__global__ __launch_bounds__(64) void transform_kernel(
        float* __restrict__ stack,       // [B, NROWS, D] in/out (raw -> sigmoid(x@W))
        const float* __restrict__ W,     // [D, D]
        float* __restrict__ mean_out) {  // [NROWS, D]
    const int row = blockIdx.x;
    const int j   = threadIdx.x;  // 0..63

    __shared__ float xs[B_N][D_N];
#pragma unroll
    for (int b = 0; b < B_N; ++b)
        xs[b][j] = stack[((long long)b * NROWS + row) * D_N + j];
    __syncthreads();

    float acc[B_N] = {0.f, 0.f, 0.f, 0.f};
#pragma unroll 8
    for (int d = 0; d < D_N; ++d) {
        float w = W[d * D_N + j];
#pragma unroll
        for (int b = 0; b < B_N; ++b)
            acc[b] += xs[b][d] * w;
    }

    float m = 0.25f * (acc[0] + acc[1] + acc[2] + acc[3]);
#pragma unroll
    for (int b = 0; b < B_N; ++b)
        stack[((long long)b * NROWS + row) * D_N + j] =
            1.0f / (1.0f + __expf(-acc[b]));
    mean_out[(long long)row * D_N + j] = 1.0f / (1.0f + __expf(-m));
}

// ---------------------------------------------------------------------------
extern "C" void kernel_launch(void* const* d_in, const int* in_sizes, int n_in,
                              void* d_out, int out_size, void* d_ws, size_t ws_size,
                              hipStream_t stream) {
    const float* user_emb = (const float*)d_in[0];
    const float* item_emb = (const float*)d_in[1];
    const int*   rows     = (const int*)  d_in[2];
    const int*   cols     = (const int*)  d_in[3];
    const float* vals     = (const float*)d_in[4];
    const float* u_w      = (const float*)d_in[5];
    const float* i_w      = (const float*)d_in[6];

    float* out = (float*)d_out;
    // Output layout (flat, return order):
    //   user_emb  [U,D]      @ 0
    //   item_emb  [I,D]      @ U*D
    //   user_embs [B,U,D]    @ U*D + I*D        (doubles as stack_u scratch)
    //   item_embs [B,I,D]    @ ... + B*U*D      (doubles as stack_i scratch)
    float* user_mean = out;
    float* item_mean = out + (long long)U_N * D_N;
    float* stack_u   = item_mean + (long long)I_N * D_N;
    float* stack_i   = stack_u + (long long)B_N * U_N * D_N;

    // Zero the (contiguous) stack regions.
    size_t stack_bytes = sizeof(float) * (size_t)B_N * (U_N + I_N) * D_N;
    hipMemsetAsync(stack_u, 0, stack_bytes, stream);

    // Phase 1: scatter
    long long nthreads = (long long)B_N * E_N * 16;
    int block = 256;
    int nblocks = (int)((nthreads + block - 1) / block);
    scatter_kernel<<<nblocks, block, 0, stream>>>(user_emb, item_emb, rows,
                                                  cols, vals, stack_u, stack_i);

    // Phase 2: transforms (in place) + means
    transform_kernel<U_N><<<U_N, 64, 0, stream>>>(stack_u, u_w, user_mean);
    transform_kernel<I_N><<<I_N, 64, 0, stream>>>(stack_i, i_w, item_mean);
}

// Round 2
// 3549.021 us; speedup vs baseline: 3.8204x; 3.8204x over previous
//
#include <hip/hip_runtime.h>

#define U_N 100000
#define I_N 50000
#define D_N 64
#define B_N 4
#define E_N 2000000

#define EDGES   (B_N * E_N)          // 8,000,000 per side
#define TOT     (2 * EDGES)          // 16,000,000 edge-entries (user + item side)
#define BU      (B_N * U_N)          // 400,000 user bins
#define BI      (B_N * I_N)          // 200,000 item bins
#define NB      (BU + BI)            // 600,000 bins total
#define SCAN_ITEMS 2048              // per scan block (256 thr x 8)
#define NBLK_A  ((NB + SCAN_ITEMS - 1) / SCAN_ITEMS)   // 293

// ---------------------------------------------------------------------------
// Pass 1: histogram — count entries per destination bin.
//   entry i < EDGES:  user side, key = b*U + rows[i]
//   entry i >= EDGES: item side, key = BU + b*I + cols[i-EDGES]
// ---------------------------------------------------------------------------
__global__ void hist_kernel(const int* __restrict__ rows,
                            const int* __restrict__ cols,
                            int* __restrict__ cnt) {
    int i = blockIdx.x * blockDim.x + threadIdx.x;
    if (i >= TOT) return;
    int k;
    if (i < EDGES) {
        int b = i / E_N;
        k = b * U_N + rows[i];
    } else {
        int e = i - EDGES;
        int b = e / E_N;
        k = BU + b * I_N + cols[e];
    }
    atomicAdd(&cnt[k], 1);
}

// ---------------------------------------------------------------------------
// Pass 2: exclusive scan over cnt[NB] -> off[NB] (and cursor copy).
// ---------------------------------------------------------------------------
__global__ __launch_bounds__(256) void scan_a(const int* __restrict__ cnt,
                                              int* __restrict__ bsum) {
    int base = blockIdx.x * SCAN_ITEMS;
    int t = threadIdx.x;
    int s = 0;
#pragma unroll
    for (int j = 0; j < 8; ++j) {
        int idx = base + t * 8 + j;
        if (idx < NB) s += cnt[idx];
    }
    __shared__ int sm[256];
    sm[t] = s; __syncthreads();
    for (int o = 128; o > 0; o >>= 1) {
        if (t < o) sm[t] += sm[t + o];
        __syncthreads();
    }
    if (t == 0) bsum[blockIdx.x] = sm[0];
}

__global__ __launch_bounds__(512) void scan_b(const int* __restrict__ bsum,
                                              int* __restrict__ bpre) {
    int t = threadIdx.x;
    __shared__ int sm[512];
    int v = (t < NBLK_A) ? bsum[t] : 0;
    sm[t] = v; __syncthreads();
    for (int o = 1; o < 512; o <<= 1) {
        int add = (t >= o) ? sm[t - o] : 0;
        __syncthreads();
        sm[t] += add;
        __syncthreads();
    }
    if (t < NBLK_A) bpre[t] = sm[t] - v;   // exclusive
}

__global__ __launch_bounds__(256) void scan_c(const int* __restrict__ cnt,
                                              const int* __restrict__ bpre,
                                              int* __restrict__ off,
                                              int* __restrict__ cursor) {
    int base = blockIdx.x * SCAN_ITEMS;
    int t = threadIdx.x;
    int loc[8];
    int s = 0;
#pragma unroll
    for (int j = 0; j < 8; ++j) {
        int idx = base + t * 8 + j;
        int c = (idx < NB) ? cnt[idx] : 0;
        loc[j] = s;
        s += c;
    }
    __shared__ int sm[256];
    int mine = s;
    sm[t] = s; __syncthreads();
    for (int o = 1; o < 256; o <<= 1) {
        int add = (t >= o) ? sm[t - o] : 0;
        __syncthreads();
        sm[t] += add;
        __syncthreads();
    }
    int tpre = sm[t] - mine;               // exclusive prefix of thread sums
    int bp = bpre[blockIdx.x];
#pragma unroll
    for (int j = 0; j < 8; ++j) {
        int idx = base + t * 8 + j;
        if (idx < NB) {
            int o = bp + tpre + loc[j];
            off[idx] = o;
            cursor[idx] = o;
        }
    }
}

// ---------------------------------------------------------------------------
// Pass 3: scatter edge ids into bin segments.
// ---------------------------------------------------------------------------
__global__ void scatter_ids_kernel(const int* __restrict__ rows,
                                   const int* __restrict__ cols,
                                   int* __restrict__ cursor,
                                   int* __restrict__ ids) {
    int i = blockIdx.x * blockDim.x + threadIdx.x;
    if (i >= TOT) return;
    int k, e;
    if (i < EDGES) {
        e = i;
        int b = e / E_N;
        k = b * U_N + rows[e];
    } else {
        e = i - EDGES;
        int b = e / E_N;
        k = BU + b * I_N + cols[e];
    }
    int pos = atomicAdd(&cursor[k], 1);
    ids[pos] = e;
}

// ---------------------------------------------------------------------------
// Pass 4: per-bin accumulation. One wave (64 lanes) per bin; lane = dim.
// Bin index k < BU  -> stack_u row k  (k = b*U + r): gather item_emb[cols[e]]
// Bin index k >= BU -> stack_i row k-BU:             gather user_emb[rows[e]]
// Every stack row is written (zeros for empty bins) -> no memset needed.
// ---------------------------------------------------------------------------
__global__ __launch_bounds__(256) void accum_kernel(
        const float* __restrict__ user_emb,
        const float* __restrict__ item_emb,
        const int* __restrict__ rows,
        const int* __restrict__ cols,
        const float* __restrict__ vals,
        const int* __restrict__ off,
        const int* __restrict__ cnt,
        const int* __restrict__ ids,
        float* __restrict__ stack_u,
        float* __restrict__ stack_i) {
    int wid  = (blockIdx.x * blockDim.x + threadIdx.x) >> 6;
    int lane = threadIdx.x & 63;
    if (wid >= NB) return;
    int start = off[wid];
    int n     = cnt[wid];
    float acc = 0.f;
    if (wid < BU) {
        int j = 0;
        for (; j + 1 < n; j += 2) {
            int e0 = ids[start + j], e1 = ids[start + j + 1];
            int c0 = cols[e0],       c1 = cols[e1];
            float v0 = vals[e0],     v1 = vals[e1];
            acc = fmaf(v0, item_emb[c0 * D_N + lane], acc);
            acc = fmaf(v1, item_emb[c1 * D_N + lane], acc);
        }
        if (j < n) {
            int e0 = ids[start + j];
            acc = fmaf(vals[e0], item_emb[cols[e0] * D_N + lane], acc);
        }
        stack_u[(long long)wid * D_N + lane] = acc;
    } else {
        int k = wid - BU;
        int j = 0;
        for (; j + 1 < n; j += 2) {
            int e0 = ids[start + j], e1 = ids[start + j + 1];
            int r0 = rows[e0],       r1 = rows[e1];
            float v0 = vals[e0],     v1 = vals[e1];
            acc = fmaf(v0, user_emb[r0 * D_N + lane], acc);
            acc = fmaf(v1, user_emb[r1 * D_N + lane], acc);
        }
        if (j < n) {
            int e0 = ids[start + j];
            acc = fmaf(vals[e0], user_emb[rows[e0] * D_N + lane], acc);
        }
        stack_i[(long long)k * D_N + lane] = acc;
    }
}

// ---------------------------------------------------------------------------
// Fallback (round-1): atomic scatter, used only if ws_size is too small.
// ---------------------------------------------------------------------------
__global__ void scatter_atomic_kernel(const float* __restrict__ user_emb,
                                      const float* __restrict__ item_emb,
                                      const int* __restrict__ rows,
                                      const int* __restrict__ cols,
                                      const float* __restrict__ vals,
                                      float* __restrict__ stack_u,
                                      float* __restrict__ stack_i) {
    long long tid = (long long)blockIdx.x * blockDim.x + threadIdx.x;
    long long e  = tid >> 4;
    int lane = (int)(tid & 15);
    if (e >= (long long)EDGES) return;
    int b = (int)(e / E_N);
    int r = rows[e];
    int c = cols[e];
    float v = vals[e];
    const float4* irow = (const float4*)(item_emb + (long long)c * D_N);
    const float4* urow = (const float4*)(user_emb + (long long)r * D_N);
    float4 iv = irow[lane];
    float4 uv = urow[lane];
    float* du = stack_u + ((long long)b * U_N + r) * D_N + lane * 4;
    float* di = stack_i + ((long long)b * I_N + c) * D_N + lane * 4;
    atomicAdd(du + 0, v * iv.x);
    atomicAdd(du + 1, v * iv.y);
    atomicAdd(du + 2, v * iv.z);
    atomicAdd(du + 3, v * iv.w);
    atomicAdd(di + 0, v * uv.x);
    atomicAdd(di + 1, v * uv.y);
    atomicAdd(di + 2, v * uv.z);
    atomicAdd(di + 3, v * uv.w);
}

// ---------------------------------------------------------------------------
// Phase 2: per-row dense transform + sigmoid, in place (unchanged).
// ---------------------------------------------------------------------------
template <int NROWS>
__global__ __launch_bounds__(64) void transform_kernel(
        float* __restrict__ stack,       // [B, NROWS, D] in/out
        const float* __restrict__ W,     // [D, D]
        float* __restrict__ mean_out) {  // [NROWS, D]
    const int row = blockIdx.x;
    const int j   = threadIdx.x;

    __shared__ float xs[B_N][D_N];
#pragma unroll
    for (int b = 0; b < B_N; ++b)
        xs[b][j] = stack[((long long)b * NROWS + row) * D_N + j];
    __syncthreads();

    float acc[B_N] = {0.f, 0.f, 0.f, 0.f};
#pragma unroll 8
    for (int d = 0; d < D_N; ++d) {
        float w = W[d * D_N + j];
#pragma unroll
        for (int b = 0; b < B_N; ++b)
            acc[b] += xs[b][d] * w;
    }

    float m = 0.25f * (acc[0] + acc[1] + acc[2] + acc[3]);
#pragma unroll
    for (int b = 0; b < B_N; ++b)
        stack[((long long)b * NROWS + row) * D_N + j] =
            1.0f / (1.0f + __expf(-acc[b]));
    mean_out[(long long)row * D_N + j] = 1.0f / (1.0f + __expf(-m));
}

// ---------------------------------------------------------------------------
extern "C" void kernel_launch(void* const* d_in, const int* in_sizes, int n_in,
                              void* d_out, int out_size, void* d_ws, size_t ws_size,
                              hipStream_t stream) {
    const float* user_emb = (const float*)d_in[0];
    const float* item_emb = (const float*)d_in[1];
    const int*   rows     = (const int*)  d_in[2];
    const int*   cols     = (const int*)  d_in[3];
    const float* vals     = (const float*)d_in[4];
    const float* u_w      = (const float*)d_in[5];
    const float* i_w      = (const float*)d_in[6];

    float* out = (float*)d_out;
    float* user_mean = out;
    float* item_mean = out + (long long)U_N * D_N;
    float* stack_u   = item_mean + (long long)I_N * D_N;  // [B,U,D] (output user_embs)
    float* stack_i   = stack_u + (long long)B_N * U_N * D_N; // [B,I,D] (output item_embs)

    // Workspace layout
    size_t needed = ((size_t)3 * NB + 2048 + (size_t)TOT) * sizeof(int);
    if (ws_size >= needed) {
        int* cnt    = (int*)d_ws;
        int* off    = cnt + NB;
        int* cursor = off + NB;
        int* bsum   = cursor + NB;      // 1024 slots
        int* bpre   = bsum + 1024;      // 1024 slots
        int* ids    = bpre + 1024;      // TOT entries

        hipMemsetAsync(cnt, 0, (size_t)NB * sizeof(int), stream);

        int block = 256;
        int nblkE = (TOT + block - 1) / block;
        hist_kernel<<<nblkE, block, 0, stream>>>(rows, cols, cnt);
        scan_a<<<NBLK_A, 256, 0, stream>>>(cnt, bsum);
        scan_b<<<1, 512, 0, stream>>>(bsum, bpre);
        scan_c<<<NBLK_A, 256, 0, stream>>>(cnt, bpre, off, cursor);
        scatter_ids_kernel<<<nblkE, block, 0, stream>>>(rows, cols, cursor, ids);

        int nblkAcc = (NB * 64 + 255) / 256;
        accum_kernel<<<nblkAcc, 256, 0, stream>>>(user_emb, item_emb, rows, cols,
                                                  vals, off, cnt, ids,
                                                  stack_u, stack_i);
    } else {
        // Fallback: atomic scatter path
        size_t stack_bytes = sizeof(float) * (size_t)B_N * (U_N + I_N) * D_N;
        hipMemsetAsync(stack_u, 0, stack_bytes, stream);
        long long nthreads = (long long)EDGES * 16;
        int block = 256;
        int nblocks = (int)((nthreads + block - 1) / block);
        scatter_atomic_kernel<<<nblocks, block, 0, stream>>>(
            user_emb, item_emb, rows, cols, vals, stack_u, stack_i);
    }

    transform_kernel<U_N><<<U_N, 64, 0, stream>>>(stack_u, u_w, user_mean);
    transform_kernel<I_N><<<I_N, 64, 0, stream>>>(stack_i, i_w, item_mean);
}